// Round 3
// baseline (12649.142 us; speedup 1.0000x reference)
//
#include <hip/hip_runtime.h>
#include <stdint.h>

// Problem dims (fixed by reference)
#define B_  128
#define T_  256
#define I_  256
#define H_  512
#define G4  2048   // 4*H
#define O_  128

using bf16x8 = __attribute__((ext_vector_type(8))) short;
using f32x4  = __attribute__((ext_vector_type(4))) float;

__device__ __forceinline__ unsigned short f2bf(float f) {
  unsigned int u = __float_as_uint(f);
  u += 0x7fffu + ((u >> 16) & 1u);   // RNE
  return (unsigned short)(u >> 16);
}
__device__ __forceinline__ float bf2f(unsigned short u) {
  return __uint_as_float((unsigned int)u << 16);
}

__device__ __forceinline__ void load_lds16(const void* g, void* l) {
  __builtin_amdgcn_global_load_lds((const __attribute__((address_space(1))) void*)g,
                                   (__attribute__((address_space(3))) void*)l, 16, 0, 0);
}

// ---------- conversions ----------
__global__ __launch_bounds__(256) void k_f32_to_bf16(const float* __restrict__ in,
                                                     unsigned short* __restrict__ out, int n4) {
  int i = blockIdx.x * 256 + threadIdx.x;
  if (i < n4) {
    float4 v = ((const float4*)in)[i];
    ushort4 o;
    o.x = f2bf(v.x); o.y = f2bf(v.y); o.z = f2bf(v.z); o.w = f2bf(v.w);
    ((ushort4*)out)[i] = o;
  }
}

__global__ __launch_bounds__(256) void k_bias(const float* __restrict__ bi0, const float* __restrict__ bh0,
                                              const float* __restrict__ bi1, const float* __restrict__ bh1,
                                              float* __restrict__ bias0, float* __restrict__ bias1) {
  int i = blockIdx.x * 256 + threadIdx.x;   // 8 blocks * 256 = 2048
  bias0[i] = bi0[i] + bh0[i];
  bias1[i] = bi1[i] + bh1[i];
}

// ---------- bf16 MFMA GEMM: C[M,N] = bf16( A[M,K] @ B[N,K]^T + bias[N] )  (m97-style) ----------
__global__ __launch_bounds__(256) void k_gemm_bt_bias(
    const unsigned short* __restrict__ A, const unsigned short* __restrict__ Bm,
    const float* __restrict__ bias, unsigned short* __restrict__ C,
    int M, int N, int K)
{
  __shared__ unsigned short As[128 * 64];   // [row][k] linear, bf16
  __shared__ unsigned short Bs[128 * 64];
  const int tid  = threadIdx.x;
  const int lane = tid & 63, wave = tid >> 6;
  const int wm = wave >> 1, wn = wave & 1;            // 2x2 wave grid
  const int m0 = blockIdx.x * 128, n0 = blockIdx.y * 128;

  f32x4 acc[4][4] = {};

  for (int k0 = 0; k0 < K; k0 += 64) {
    // stage 128x64 bf16 tiles of A and B via async global->LDS (16B/lane)
#pragma unroll
    for (int i = 0; i < 4; ++i) {
      int o  = i * 4096 + wave * 1024 + lane * 16;    // byte offset in tile
      int r  = o >> 7;                                // row (128B rows)
      int cb = (o & 127) >> 1;                        // bf16 col
      load_lds16(A  + (size_t)(m0 + r) * K + k0 + cb, &As[i * 2048 + wave * 512]);
      load_lds16(Bm + (size_t)(n0 + r) * K + k0 + cb, &Bs[i * 2048 + wave * 512]);
    }
    __syncthreads();

    bf16x8 af[4][2], bfr[4][2];
#pragma unroll
    for (int mt = 0; mt < 4; ++mt)
#pragma unroll
      for (int kc = 0; kc < 2; ++kc) {
        int ra = wm * 64 + mt * 16 + (lane & 15);
        int rb = wn * 64 + mt * 16 + (lane & 15);
        int kk = kc * 32 + (lane >> 4) * 8;
        af[mt][kc]  = *(const bf16x8*)&As[ra * 64 + kk];
        bfr[mt][kc] = *(const bf16x8*)&Bs[rb * 64 + kk];
      }
#pragma unroll
    for (int kc = 0; kc < 2; ++kc)
#pragma unroll
      for (int mt = 0; mt < 4; ++mt)
#pragma unroll
        for (int nt = 0; nt < 4; ++nt)
          acc[mt][nt] = __builtin_amdgcn_mfma_f32_16x16x32_bf16(af[mt][kc], bfr[nt][kc], acc[mt][nt], 0, 0, 0);
    __syncthreads();
  }

  // epilogue: C/D layout col=lane&15, row=(lane>>4)*4+reg (m89-verified)
#pragma unroll
  for (int mt = 0; mt < 4; ++mt) {
    int rb0 = m0 + wm * 64 + mt * 16 + (lane >> 4) * 4;
#pragma unroll
    for (int nt = 0; nt < 4; ++nt) {
      int col = n0 + wn * 64 + nt * 16 + (lane & 15);
      float bv = bias[col];
#pragma unroll
      for (int r = 0; r < 4; ++r)
        C[(size_t)(rb0 + r) * N + col] = f2bf(acc[mt][nt][r] + bv);
    }
  }
}

// ---------- one LSTM timestep (fp32 math). grid (B/32, H/8), block 256 ----------
// pre[b][g] = xp[b][t][g] + sum_k h_in[b][k]*Whh[g][k]; gates i,f,g,o; c,h update.
// hT layout: [b][k] f32, 16B-block XOR swizzle on k so the 32 lanes of a
// fixed-k read spread across all 8 16B bank-slots -> ds_read_b128 per 4-k.
__global__ __launch_bounds__(256) void k_lstm_step(
    const unsigned short* __restrict__ xp, const float* __restrict__ Whh,
    const float* __restrict__ h_in, float* __restrict__ h_out,
    float* __restrict__ c, unsigned short* __restrict__ hseq, int t)
{
  __shared__ float hT[32 * 512];   // 64 KB
  const int tid = threadIdx.x;
  const int bi = tid & 31;          // batch within 32-tile
  const int ji = tid >> 5;          // hidden within 8-tile
  const int b0 = blockIdx.x * 32;
  const int j0 = blockIdx.y * 8;

  // stage h_in[b0..b0+31][0..511] (coalesced float4 reads, swizzled writes)
#pragma unroll
  for (int i = 0; i < 16; ++i) {
    int idx4 = i * 256 + tid;
    int b = idx4 >> 7;              // 128 float4 per row
    int k = (idx4 & 127) << 2;
    float4 v = ((const float4*)h_in)[(size_t)(b0 + b) * 128 + (idx4 & 127)];
    *(float4*)&hT[(b << 9) | (k ^ ((b & 7) << 2))] = v;
  }
  __syncthreads();

  const int j = j0 + ji;
  const float* w0 = Whh + (size_t)(j)        * 512;
  const float* w1 = Whh + (size_t)(512 + j)  * 512;
  const float* w2 = Whh + (size_t)(1024 + j) * 512;
  const float* w3 = Whh + (size_t)(1536 + j) * 512;
  const float* hb = &hT[bi << 9];
  const int xm = (bi & 7) << 2;
  float a0 = 0.f, a1 = 0.f, a2 = 0.f, a3 = 0.f;
#pragma unroll 8
  for (int k = 0; k < 512; k += 4) {
    f32x4 h4 = *(const f32x4*)&hb[k ^ xm];
    float4 v0 = *(const float4*)&w0[k];
    float4 v1 = *(const float4*)&w1[k];
    float4 v2 = *(const float4*)&w2[k];
    float4 v3 = *(const float4*)&w3[k];
    a0 += h4[0] * v0.x + h4[1] * v0.y + h4[2] * v0.z + h4[3] * v0.w;
    a1 += h4[0] * v1.x + h4[1] * v1.y + h4[2] * v1.z + h4[3] * v1.w;
    a2 += h4[0] * v2.x + h4[1] * v2.y + h4[2] * v2.z + h4[3] * v2.w;
    a3 += h4[0] * v3.x + h4[1] * v3.y + h4[2] * v3.z + h4[3] * v3.w;
  }

  const int b = b0 + bi;
  const unsigned short* xr = xp + ((size_t)b * T_ + t) * G4;
  float pi = bf2f(xr[j])          + a0;
  float pf = bf2f(xr[512 + j])    + a1;
  float pg = bf2f(xr[1024 + j])   + a2;
  float po = bf2f(xr[1536 + j])   + a3;
  float gi = 1.f / (1.f + __expf(-pi));
  float gf = 1.f / (1.f + __expf(-pf));
  float gg = 1.f - 2.f / (__expf(2.f * pg) + 1.f);   // tanh
  float go = 1.f / (1.f + __expf(-po));
  size_t sidx = (size_t)b * 512 + j;
  float cc = gf * c[sidx] + gi * gg;
  c[sidx] = cc;
  float hh = go * (1.f - 2.f / (__expf(2.f * cc) + 1.f));
  h_out[sidx] = hh;
  if (hseq) hseq[((size_t)b * T_ + t) * 512 + j] = f2bf(hh);
}

// ---------- final FC: out[b][o] = h2[b][:] . fcw[o][:] + fcb[o] ----------
__global__ __launch_bounds__(256) void k_fc(const float* __restrict__ h2,
                                            const float* __restrict__ w,
                                            const float* __restrict__ bias,
                                            float* __restrict__ out) {
  int idx = blockIdx.x * 256 + threadIdx.x;   // 64 blocks -> 16384 outputs
  int b = idx >> 7, o = idx & 127;
  const float* hr = h2 + (size_t)b * 512;
  const float* wr = w  + (size_t)o * 512;
  float acc = 0.f;
#pragma unroll 8
  for (int k = 0; k < 512; k += 4) {
    float4 hv = *(const float4*)&hr[k];
    float4 wv = *(const float4*)&wr[k];
    acc += hv.x * wv.x + hv.y * wv.y + hv.z * wv.z + hv.w * wv.w;
  }
  out[idx] = acc + bias[o];
}

extern "C" void kernel_launch(void* const* d_in, const int* in_sizes, int n_in,
                              void* d_out, int out_size, void* d_ws, size_t ws_size,
                              hipStream_t stream) {
  const float* x    = (const float*)d_in[0];
  const float* Wih0 = (const float*)d_in[1];
  const float* Whh0 = (const float*)d_in[2];
  const float* bih0 = (const float*)d_in[3];
  const float* bhh0 = (const float*)d_in[4];
  const float* Wih1 = (const float*)d_in[5];
  const float* Whh1 = (const float*)d_in[6];
  const float* bih1 = (const float*)d_in[7];
  const float* bhh1 = (const float*)d_in[8];
  const float* fcw  = (const float*)d_in[9];
  const float* fcb  = (const float*)d_in[10];
  float* out = (float*)d_out;

  // workspace layout (~181 MB total)
  char* ws = (char*)d_ws;
  size_t off = 0;
  auto alloc = [&](size_t bytes) {
    void* p = ws + off;
    off = (off + bytes + 255) & ~(size_t)255;
    return p;
  };
  unsigned short* xp    = (unsigned short*)alloc((size_t)B_ * T_ * G4 * 2);  // 128 MiB, reused both layers
  unsigned short* xb    = (unsigned short*)alloc((size_t)B_ * T_ * I_ * 2);
  unsigned short* wih0b = (unsigned short*)alloc((size_t)G4 * I_ * 2);
  unsigned short* wih1b = (unsigned short*)alloc((size_t)G4 * H_ * 2);
  unsigned short* h1seq = (unsigned short*)alloc((size_t)B_ * T_ * H_ * 2);
  float* bias0 = (float*)alloc((size_t)G4 * 4);
  float* bias1 = (float*)alloc((size_t)G4 * 4);
  const size_t st_bytes = (size_t)B_ * H_ * 4;
  float* s0a = (float*)alloc(st_bytes);
  float* s0b = (float*)alloc(st_bytes);
  float* c0  = (float*)alloc(st_bytes);
  float* s1a = (float*)alloc(st_bytes);
  float* s1b = (float*)alloc(st_bytes);
  float* c1  = (float*)alloc(st_bytes);

  // zero the t=0 read-state and cell states (ws is poisoned 0xAA each call)
  hipMemsetAsync(s0a, 0, st_bytes, stream);
  hipMemsetAsync(c0,  0, st_bytes, stream);
  hipMemsetAsync(s1a, 0, st_bytes, stream);
  hipMemsetAsync(c1,  0, st_bytes, stream);

  // conversions to bf16
  k_f32_to_bf16<<<(B_ * T_ * I_ / 4 + 255) / 256, 256, 0, stream>>>(x, xb, B_ * T_ * I_ / 4);
  k_f32_to_bf16<<<(G4 * I_ / 4 + 255) / 256, 256, 0, stream>>>(Wih0, wih0b, G4 * I_ / 4);
  k_f32_to_bf16<<<(G4 * H_ / 4 + 255) / 256, 256, 0, stream>>>(Wih1, wih1b, G4 * H_ / 4);
  k_bias<<<G4 / 256, 256, 0, stream>>>(bih0, bhh0, bih1, bhh1, bias0, bias1);

  // layer 0 input projection: xp = bf16(xb @ Wih0^T + (bih0+bhh0))
  dim3 gg(B_ * T_ / 128, G4 / 128);
  k_gemm_bt_bias<<<gg, 256, 0, stream>>>(xb, wih0b, bias0, xp, B_ * T_, G4, I_);

  // layer 0 scan
  dim3 gs(B_ / 32, H_ / 8);
  for (int t = 0; t < T_; ++t) {
    const float* hin = (t & 1) ? s0b : s0a;
    float*      hout = (t & 1) ? s0a : s0b;
    k_lstm_step<<<gs, 256, 0, stream>>>(xp, Whh0, hin, hout, c0, h1seq, t);
  }

  // layer 1 input projection: xp = bf16(h1seq @ Wih1^T + (bih1+bhh1))
  k_gemm_bt_bias<<<gg, 256, 0, stream>>>(h1seq, wih1b, bias1, xp, B_ * T_, G4, H_);

  // layer 1 scan (no sequence output needed)
  for (int t = 0; t < T_; ++t) {
    const float* hin = (t & 1) ? s1b : s1a;
    float*      hout = (t & 1) ? s1a : s1b;
    k_lstm_step<<<gs, 256, 0, stream>>>(xp, Whh1, hin, hout, c1, (unsigned short*)nullptr, t);
  }

  // final FC on h2[T-1]  (t=255 odd -> wrote s1a)
  k_fc<<<(B_ * O_) / 256, 256, 0, stream>>>(s1a, fcw, fcb, out);
}

// Round 14
// 6579.341 us; speedup vs baseline: 1.9226x; 1.9226x over previous
//
#include <hip/hip_runtime.h>
#include <stdint.h>

// Problem dims (fixed by reference)
#define B_  128
#define T_  256
#define I_  256
#define H_  512
#define G4  2048   // 4*H
#define O_  128

using bf16x8 = __attribute__((ext_vector_type(8))) short;
using f32x4  = __attribute__((ext_vector_type(4))) float;

static __device__ __forceinline__ unsigned short f2bf(float f) {
  unsigned int u = __float_as_uint(f);
  u += 0x7fffu + ((u >> 16) & 1u);   // RNE
  return (unsigned short)(u >> 16);
}
static __device__ __forceinline__ float bf2f(unsigned short u) {
  return __uint_as_float((unsigned int)u << 16);
}

__device__ __forceinline__ void load_lds16(const void* g, void* l) {
  __builtin_amdgcn_global_load_lds((const __attribute__((address_space(1))) void*)g,
                                   (__attribute__((address_space(3))) void*)l, 16, 0, 0);
}

// ---------- conversions ----------
__global__ __launch_bounds__(256) void k_f32_to_bf16(const float* __restrict__ in,
                                                     unsigned short* __restrict__ out, int n4) {
  int i = blockIdx.x * 256 + threadIdx.x;
  if (i < n4) {
    float4 v = ((const float4*)in)[i];
    ushort4 o;
    o.x = f2bf(v.x); o.y = f2bf(v.y); o.z = f2bf(v.z); o.w = f2bf(v.w);
    ((ushort4*)out)[i] = o;
  }
}

__global__ __launch_bounds__(256) void k_bias(const float* __restrict__ bi0, const float* __restrict__ bh0,
                                              const float* __restrict__ bi1, const float* __restrict__ bh1,
                                              float* __restrict__ bias0, float* __restrict__ bias1) {
  int i = blockIdx.x * 256 + threadIdx.x;   // 8 blocks * 256 = 2048
  bias0[i] = bi0[i] + bh0[i];
  bias1[i] = bi1[i] + bh1[i];
}

// ---------- bf16 MFMA GEMM: C[M,N] = bf16( A[M,K] @ B[N,K]^T + bias[N] )  (m97-style) ----------
__global__ __launch_bounds__(256) void k_gemm_bt_bias(
    const unsigned short* __restrict__ A, const unsigned short* __restrict__ Bm,
    const float* __restrict__ bias, unsigned short* __restrict__ C,
    int M, int N, int K)
{
  __shared__ unsigned short As[128 * 64];   // [row][k] linear, bf16
  __shared__ unsigned short Bs[128 * 64];
  const int tid  = threadIdx.x;
  const int lane = tid & 63, wave = tid >> 6;
  const int wm = wave >> 1, wn = wave & 1;            // 2x2 wave grid
  const int m0 = blockIdx.x * 128, n0 = blockIdx.y * 128;

  f32x4 acc[4][4] = {};

  for (int k0 = 0; k0 < K; k0 += 64) {
#pragma unroll
    for (int i = 0; i < 4; ++i) {
      int o  = i * 4096 + wave * 1024 + lane * 16;    // byte offset in tile
      int r  = o >> 7;                                // row (128B rows)
      int cb = (o & 127) >> 1;                        // bf16 col
      load_lds16(A  + (size_t)(m0 + r) * K + k0 + cb, &As[i * 2048 + wave * 512]);
      load_lds16(Bm + (size_t)(n0 + r) * K + k0 + cb, &Bs[i * 2048 + wave * 512]);
    }
    __syncthreads();

    bf16x8 af[4][2], bfr[4][2];
#pragma unroll
    for (int mt = 0; mt < 4; ++mt)
#pragma unroll
      for (int kc = 0; kc < 2; ++kc) {
        int ra = wm * 64 + mt * 16 + (lane & 15);
        int rb = wn * 64 + mt * 16 + (lane & 15);
        int kk = kc * 32 + (lane >> 4) * 8;
        af[mt][kc]  = *(const bf16x8*)&As[ra * 64 + kk];
        bfr[mt][kc] = *(const bf16x8*)&Bs[rb * 64 + kk];
      }
#pragma unroll
    for (int kc = 0; kc < 2; ++kc)
#pragma unroll
      for (int mt = 0; mt < 4; ++mt)
#pragma unroll
        for (int nt = 0; nt < 4; ++nt)
          acc[mt][nt] = __builtin_amdgcn_mfma_f32_16x16x32_bf16(af[mt][kc], bfr[nt][kc], acc[mt][nt], 0, 0, 0);
    __syncthreads();
  }

#pragma unroll
  for (int mt = 0; mt < 4; ++mt) {
    int rb0 = m0 + wm * 64 + mt * 16 + (lane >> 4) * 4;
#pragma unroll
    for (int nt = 0; nt < 4; ++nt) {
      int col = n0 + wn * 64 + nt * 16 + (lane & 15);
      float bv = bias[col];
#pragma unroll
      for (int r = 0; r < 4; ++r)
        C[(size_t)(rb0 + r) * N + col] = f2bf(acc[mt][nt][r] + bv);
    }
  }
}

// ---------- persistent scan kernel ----------
// 256 blocks (1/CU): 8 batch-groups (bid&7) x 32 j-blocks (bid>>3).
// Block = 16 batch x 16 hidden outputs; 4 waves = 4 gates (i,f,g,o).
// Whh held in VGPRs as bf16 hi/lo split; recurrent GEMM via 3-product MFMA.
// h exchanged via AGENT-scope atomic load/store (device-coherent, L1-bypassing)
// + per-group release/acquire barrier (fence + device-scope atomic counter).
__global__ __launch_bounds__(256, 1) void k_scan(
    const float* __restrict__ Whh,         // [2048][512] f32
    const unsigned short* __restrict__ xp, // [B][T][2048] bf16 (proj + biases)
    unsigned int* __restrict__ bufA,       // [128][512] packed h (t even input)
    unsigned int* __restrict__ bufB,
    unsigned short* __restrict__ hseq,     // layer0 out: [B][T][512] bf16, or null
    float* __restrict__ h2last,            // layer1 out: [B][512] f32, or null
    unsigned int* __restrict__ cnt)        // 8 counters, zeroed
{
  __shared__ __align__(16) unsigned short hiT[16 * 512];  // swizzled [b][k] bf16
  __shared__ __align__(16) unsigned short loT[16 * 512];
  __shared__ float pregate[4][16][16];

  const int tid  = threadIdx.x;
  const int lane = tid & 63;
  const int g    = tid >> 6;           // wave index = gate (i,f,g,o)
  const int gb   = blockIdx.x & 7;     // batch-group
  const int jb   = blockIdx.x >> 3;    // 0..31
  const int b0   = gb * 16;
  const int j0   = jb * 16;

  // --- load persistent Whh B-fragments (hi/lo bf16 split), 128 VGPR/lane ---
  bf16x8 bwhi[16], bwlo[16];
  {
    const float* wr = Whh + ((size_t)g * 512 + j0 + (lane & 15)) * 512 + ((lane >> 4) * 8);
#pragma unroll
    for (int s = 0; s < 16; ++s) {
      float4 v0 = *(const float4*)(wr + s * 32);
      float4 v1 = *(const float4*)(wr + s * 32 + 4);
      float vv[8] = {v0.x, v0.y, v0.z, v0.w, v1.x, v1.y, v1.z, v1.w};
#pragma unroll
      for (int e = 0; e < 8; ++e) {
        unsigned short hi = f2bf(vv[e]);
        bwhi[s][e] = (short)hi;
        bwlo[s][e] = (short)f2bf(vv[e] - bf2f(hi));
      }
    }
  }

  // gate-phase thread mapping: (bb, jj) owns c[b0+bb][j0+jj]
  const int bb = tid >> 4;
  const int jj = tid & 15;
  float creg = 0.f;

  // xp prefetch (acc mapping: lane, reg r -> b = b0+(lane>>4)*4+r, j = j0+(lane&15))
  const unsigned short* xq = xp + g * 512 + j0 + (lane & 15);
  const size_t bbase = (size_t)(b0 + (lane >> 4) * 4);
  unsigned short pxc[4], pxn[4];
#pragma unroll
  for (int r = 0; r < 4; ++r) pxc[r] = xq[((bbase + r) * T_ + 0) * G4];

  const int abase = ((lane & 15) << 10) + ((lane >> 4) << 4);
  const int asw   = (lane & 7) << 4;    // ((row&7)<<4), row = lane&15

  for (int t = 0; t < T_; ++t) {
    const unsigned int* bufC = (t & 1) ? bufB : bufA;   // holds h_{t-1}
    unsigned int* bufN       = (t & 1) ? bufA : bufB;   // receives h_t

    // --- stage h tile (16 rows x 512) hi/lo into swizzled LDS ---
    // AGENT-scope scalar loads: L1-bypassing + cross-XCD coherent.
#pragma unroll
    for (int i = 0; i < 8; ++i) {
      int flat = i * 256 + tid;          // uint4-chunk id, 2048 total
      int row  = flat >> 7;              // 0..15
      int c4   = flat & 127;             // 4-uint chunk within row
      const unsigned int* src = bufC + (size_t)(b0 + row) * 512 + c4 * 4;
      unsigned int e0 = __hip_atomic_load(src + 0, __ATOMIC_RELAXED, __HIP_MEMORY_SCOPE_AGENT);
      unsigned int e1 = __hip_atomic_load(src + 1, __ATOMIC_RELAXED, __HIP_MEMORY_SCOPE_AGENT);
      unsigned int e2 = __hip_atomic_load(src + 2, __ATOMIC_RELAXED, __HIP_MEMORY_SCOPE_AGENT);
      unsigned int e3 = __hip_atomic_load(src + 3, __ATOMIC_RELAXED, __HIP_MEMORY_SCOPE_AGENT);
      int sw = ((row << 10) + (c4 << 3)) ^ ((row & 7) << 4);
      ushort4 hi4, lo4;
      hi4.x = e0 & 0xffff; lo4.x = e0 >> 16;
      hi4.y = e1 & 0xffff; lo4.y = e1 >> 16;
      hi4.z = e2 & 0xffff; lo4.z = e2 >> 16;
      hi4.w = e3 & 0xffff; lo4.w = e3 >> 16;
      *(ushort4*)((char*)hiT + sw) = hi4;
      *(ushort4*)((char*)loT + sw) = lo4;
    }
    __syncthreads();

    // prefetch next step's xp (hidden under k-loop + exchange)
    const int tn = (t + 1 < T_) ? t + 1 : t;
#pragma unroll
    for (int r = 0; r < 4; ++r) pxn[r] = xq[((bbase + r) * T_ + tn) * G4];

    // --- recurrent GEMM: 3 interleaved MFMA chains (hi*hi + lo*hi + hi*lo) ---
    f32x4 acc0 = {0.f,0.f,0.f,0.f}, acc1 = {0.f,0.f,0.f,0.f}, acc2 = {0.f,0.f,0.f,0.f};
#pragma unroll
    for (int s = 0; s < 16; ++s) {
      int off = (abase + (s << 6)) ^ asw;
      bf16x8 ah = *(const bf16x8*)((const char*)hiT + off);
      bf16x8 al = *(const bf16x8*)((const char*)loT + off);
      acc0 = __builtin_amdgcn_mfma_f32_16x16x32_bf16(ah, bwhi[s], acc0, 0, 0, 0);
      acc1 = __builtin_amdgcn_mfma_f32_16x16x32_bf16(al, bwhi[s], acc1, 0, 0, 0);
      acc2 = __builtin_amdgcn_mfma_f32_16x16x32_bf16(ah, bwlo[s], acc2, 0, 0, 0);
    }

#pragma unroll
    for (int r = 0; r < 4; ++r)
      pregate[g][(lane >> 4) * 4 + r][lane & 15] = acc0[r] + acc1[r] + acc2[r] + bf2f(pxc[r]);
    __syncthreads();

    // --- gate phase: thread (bb, jj) ---
    float pi = pregate[0][bb][jj];
    float pf = pregate[1][bb][jj];
    float pg = pregate[2][bb][jj];
    float po = pregate[3][bb][jj];
    float gi = 1.f / (1.f + __expf(-pi));
    float gf = 1.f / (1.f + __expf(-pf));
    float gg = 1.f - 2.f / (__expf(2.f * pg) + 1.f);   // tanh
    float go = 1.f / (1.f + __expf(-po));
    creg = gf * creg + gi * gg;
    float hh = go * (1.f - 2.f / (__expf(2.f * creg) + 1.f));
    unsigned short hhi = f2bf(hh);
    unsigned short hlo = f2bf(hh - bf2f(hhi));
    unsigned int packed = (unsigned int)hhi | ((unsigned int)hlo << 16);
    __hip_atomic_store(&bufN[(size_t)(b0 + bb) * 512 + j0 + jj], packed,
                       __ATOMIC_RELAXED, __HIP_MEMORY_SCOPE_AGENT);
    if (hseq)   hseq[((size_t)(b0 + bb) * T_ + t) * 512 + j0 + jj] = hhi;
    if (h2last && t == T_ - 1) h2last[(size_t)(b0 + bb) * 512 + j0 + jj] = hh;

#pragma unroll
    for (int r = 0; r < 4; ++r) pxc[r] = pxn[r];

    __syncthreads();   // pregate reads done; all h stores issued+drained

    // --- group barrier: 32 j-blocks sharing this batch-group ---
    if (t < T_ - 1) {
      if (tid == 0) {
        __builtin_amdgcn_fence(__ATOMIC_RELEASE, "agent");
        atomicAdd(&cnt[gb], 1u);                        // device-scope (G12)
        const unsigned int tgt = 32u * (unsigned int)(t + 1);
        unsigned int spins = 0;
        while (__hip_atomic_load(&cnt[gb], __ATOMIC_ACQUIRE, __HIP_MEMORY_SCOPE_AGENT) < tgt) {
          __builtin_amdgcn_s_sleep(8);
          if (++spins > (1u << 17)) break;              // bounded escape: no hangs
        }
        __builtin_amdgcn_fence(__ATOMIC_ACQUIRE, "agent");
      }
      __syncthreads();
    }
  }
}

// ---------- final FC: out[b][o] = h2[b][:] . fcw[o][:] + fcb[o] ----------
__global__ __launch_bounds__(256) void k_fc(const float* __restrict__ h2,
                                            const float* __restrict__ w,
                                            const float* __restrict__ bias,
                                            float* __restrict__ out) {
  int idx = blockIdx.x * 256 + threadIdx.x;   // 64 blocks -> 16384 outputs
  int b = idx >> 7, o = idx & 127;
  const float* hr = h2 + (size_t)b * 512;
  const float* wr = w  + (size_t)o * 512;
  float acc = 0.f;
#pragma unroll 8
  for (int k = 0; k < 512; k += 4) {
    float4 hv = *(const float4*)&hr[k];
    float4 wv = *(const float4*)&wr[k];
    acc += hv.x * wv.x + hv.y * wv.y + hv.z * wv.z + hv.w * wv.w;
  }
  out[idx] = acc + bias[o];
}

static void launch_scan(const float* whh, const unsigned short* xpc,
                        unsigned int* a, unsigned int* b,
                        unsigned short* hs, float* h2, unsigned int* c,
                        hipStream_t stream) {
  void* args[] = {(void*)&whh, (void*)&xpc, (void*)&a, (void*)&b,
                  (void*)&hs, (void*)&h2, (void*)&c};
  hipError_t e = hipLaunchCooperativeKernel((const void*)k_scan, dim3(256), dim3(256),
                                            args, 0, stream);
  if (e != hipSuccess) {
    // fallback: plain launch (grid == CU count, 1 block/CU -> co-resident)
    k_scan<<<dim3(256), dim3(256), 0, stream>>>(whh, xpc, a, b, hs, h2, c);
  }
}

extern "C" void kernel_launch(void* const* d_in, const int* in_sizes, int n_in,
                              void* d_out, int out_size, void* d_ws, size_t ws_size,
                              hipStream_t stream) {
  const float* x    = (const float*)d_in[0];
  const float* Wih0 = (const float*)d_in[1];
  const float* Whh0 = (const float*)d_in[2];
  const float* bih0 = (const float*)d_in[3];
  const float* bhh0 = (const float*)d_in[4];
  const float* Wih1 = (const float*)d_in[5];
  const float* Whh1 = (const float*)d_in[6];
  const float* bih1 = (const float*)d_in[7];
  const float* bhh1 = (const float*)d_in[8];
  const float* fcw  = (const float*)d_in[9];
  const float* fcb  = (const float*)d_in[10];
  float* out = (float*)d_out;

  // workspace layout (~182 MB total)
  char* ws = (char*)d_ws;
  size_t off = 0;
  auto alloc = [&](size_t bytes) {
    void* p = ws + off;
    off = (off + bytes + 255) & ~(size_t)255;
    return p;
  };
  unsigned short* xp    = (unsigned short*)alloc((size_t)B_ * T_ * G4 * 2);  // 128 MiB
  unsigned short* xb    = (unsigned short*)alloc((size_t)B_ * T_ * I_ * 2);
  unsigned short* wih0b = (unsigned short*)alloc((size_t)G4 * I_ * 2);
  unsigned short* wih1b = (unsigned short*)alloc((size_t)G4 * H_ * 2);
  unsigned short* h1seq = (unsigned short*)alloc((size_t)B_ * T_ * H_ * 2);
  float* bias0 = (float*)alloc((size_t)G4 * 4);
  float* bias1 = (float*)alloc((size_t)G4 * 4);
  unsigned int* hA     = (unsigned int*)alloc((size_t)B_ * H_ * 4);
  unsigned int* hB     = (unsigned int*)alloc((size_t)B_ * H_ * 4);
  float*        h2last = (float*)alloc((size_t)B_ * H_ * 4);
  unsigned int* cnt    = (unsigned int*)alloc(64);   // 8 + 8 counters

  // zero t=0 h-input and counters (ws poisoned 0xAA every call)
  hipMemsetAsync(hA,  0, (size_t)B_ * H_ * 4, stream);
  hipMemsetAsync(cnt, 0, 64, stream);

  // conversions to bf16
  k_f32_to_bf16<<<(B_ * T_ * I_ / 4 + 255) / 256, 256, 0, stream>>>(x, xb, B_ * T_ * I_ / 4);
  k_f32_to_bf16<<<(G4 * I_ / 4 + 255) / 256, 256, 0, stream>>>(Wih0, wih0b, G4 * I_ / 4);
  k_f32_to_bf16<<<(G4 * H_ / 4 + 255) / 256, 256, 0, stream>>>(Wih1, wih1b, G4 * H_ / 4);
  k_bias<<<G4 / 256, 256, 0, stream>>>(bih0, bhh0, bih1, bhh1, bias0, bias1);

  // layer 0 input projection: xp = bf16(xb @ Wih0^T + (bih0+bhh0))
  dim3 gg(B_ * T_ / 128, G4 / 128);
  k_gemm_bt_bias<<<gg, 256, 0, stream>>>(xb, wih0b, bias0, xp, B_ * T_, G4, I_);

  // layer 0 persistent scan
  launch_scan(Whh0, xp, hA, hB, h1seq, nullptr, cnt, stream);

  // layer 1 input projection: xp = bf16(h1seq @ Wih1^T + (bih1+bhh1))
  k_gemm_bt_bias<<<gg, 256, 0, stream>>>(h1seq, wih1b, bias1, xp, B_ * T_, G4, H_);

  // re-zero t=0 h-input for layer 1 (scan1 uses cnt+8, still zero)
  hipMemsetAsync(hA, 0, (size_t)B_ * H_ * 4, stream);

  // layer 1 persistent scan
  launch_scan(Whh1, xp, hA, hB, nullptr, h2last, cnt + 8, stream);

  // final FC
  k_fc<<<(B_ * O_) / 256, 256, 0, stream>>>(h2last, fcw, fcb, out);
}